// Round 21
// baseline (242.553 us; speedup 1.0000x reference)
//
#include <hip/hip_runtime.h>
#include <hip/hip_fp16.h>

// Problem constants: B=16, L=4096, H=8, E=64, K=64, F=2049 (rfft bins)
// Only bins m in [1,2048] matter (bin 0 excluded from top-k; out_ft uses slots 0..63).

#define NTHREADS 256

typedef _Float16 f16x8 __attribute__((ext_vector_type(8)));
typedef float    f32x4 __attribute__((ext_vector_type(4)));

// LDS-only barrier: drains LDS ops (lgkmcnt) but leaves global loads/stores in flight.
__device__ inline void lds_barrier() {
    asm volatile("s_waitcnt lgkmcnt(0)" ::: "memory");
    __builtin_amdgcn_s_barrier();
}

// LDS swizzle for the FFT working array: flips bits 1-3 by bits 4-6 (bijective, disjoint).
// Preserves bit 0, so (2s, 2s+1) pairs stay contiguous -> b128 pair stores are legal.
#define ZI(i) ((i) ^ ((((i) >> 4) & 7) << 1))

__device__ inline float2 f2add(float2 a, float2 b) { return make_float2(a.x + b.x, a.y + b.y); }
__device__ inline float2 f2sub(float2 a, float2 b) { return make_float2(a.x - b.x, a.y - b.y); }
// complex mul, exactly 4 VALU (mul, fma, mul, fma)
__device__ inline float2 cmulf(float2 a, float2 b) {
    return make_float2(__builtin_fmaf(a.x, b.x, -(a.y * b.y)),
                       __builtin_fmaf(a.x, b.y,  a.y * b.x));
}

// radix-16 DIT butterfly on 16 points (4 stages st..st+3 in registers).
__device__ inline void radix16(float2 x[16], float2 tA, float2 tB, float2 tC, float2 tD) {
#pragma unroll
    for (int q = 0; q < 8; ++q) {
        float2 v = cmulf(tA, x[2 * q + 1]);
        float2 u = x[2 * q];
        x[2 * q]     = f2add(u, v);
        x[2 * q + 1] = f2sub(u, v);
    }
    {
        float2 tB1 = make_float2(tB.y, -tB.x);
#pragma unroll
        for (int q = 0; q < 4; ++q) {
            {
                float2 v = cmulf(tB, x[4 * q + 2]);
                float2 u = x[4 * q];
                x[4 * q]     = f2add(u, v);
                x[4 * q + 2] = f2sub(u, v);
            }
            {
                float2 v = cmulf(tB1, x[4 * q + 3]);
                float2 u = x[4 * q + 1];
                x[4 * q + 1] = f2add(u, v);
                x[4 * q + 3] = f2sub(u, v);
            }
        }
    }
    {
        const float C = 0.70710678118654752f;
        float2 w0 = tC;
        float2 w1 = cmulf(tC, make_float2(C, -C));
        float2 w2 = make_float2(tC.y, -tC.x);
        float2 w3 = cmulf(tC, make_float2(-C, -C));
#pragma unroll
        for (int q = 0; q < 2; ++q) {
            float2 ws[4] = {w0, w1, w2, w3};
#pragma unroll
            for (int r = 0; r < 4; ++r) {
                float2 v = cmulf(ws[r], x[8 * q + r + 4]);
                float2 u = x[8 * q + r];
                x[8 * q + r]     = f2add(u, v);
                x[8 * q + r + 4] = f2sub(u, v);
            }
        }
    }
    {
        const float C  = 0.70710678118654752f;
        const float C1 = 0.92387953251128676f;  // cos(pi/8)
        const float S1 = 0.38268343236508977f;  // sin(pi/8)
        float2 wD[8];
        wD[0] = tD;
        wD[1] = cmulf(tD, make_float2(C1, -S1));
        wD[2] = cmulf(tD, make_float2(C, -C));
        wD[3] = cmulf(tD, make_float2(S1, -C1));
        wD[4] = make_float2(tD.y, -tD.x);
        wD[5] = cmulf(tD, make_float2(-S1, -C1));
        wD[6] = cmulf(tD, make_float2(-C, -C));
        wD[7] = cmulf(tD, make_float2(-C1, -S1));
#pragma unroll
        for (int r = 0; r < 8; ++r) {
            float2 v = cmulf(wD[r], x[r + 8]);
            float2 u = x[r];
            x[r]     = f2add(u, v);
            x[r + 8] = f2sub(u, v);
        }
    }
}

// ---------------- init: trig (f64-accurate) + score zeroing + fp16 Af matrix ------------------
__global__ __launch_bounds__(256) void k_init(float2* __restrict__ trig,
                                              unsigned long long* __restrict__ score,
                                              _Float16* __restrict__ Af) {
    const int g = blockIdx.x * 256 + threadIdx.x;
    if (g < 4096) {
        double th = (6.283185307179586476925286766559 * (double)g) / 4096.0;
        trig[g] = make_float2((float)cos(th), (float)sin(th));
        if (g < 2048) score[g] = 0ULL;
    } else {
        const int gid = g - 4096;           // 0 .. 524287
        const int l = gid >> 7, k = gid & 127;
        const int kk = (k < 64) ? k : k - 64;
        const int ph = (kk * l) & 4095;
        const float th = 1.5339807878856412e-3f * (float)ph;  // 2*pi/4096
        float v = (k < 64) ? __cosf(th) : -__sinf(th);
        Af[gid] = (_Float16)v;
    }
}

// ---------------- transpose + bit-reversal: q[b,l,h,e] -> T[(b,h,eo)][p][j] (float2) -----------
__global__ __launch_bounds__(256) void k_xpose(const float* __restrict__ q,
                                               float2* __restrict__ T) {
    __shared__ float tile[128][65];  // 33 KB, padded (+1)

    const int tid = threadIdx.x;
    const int bi  = blockIdx.x;
    const int b   = bi >> 8;
    const int h   = (bi >> 5) & 7;
    const int c5  = bi & 31;

    const float* qb = q + ((size_t)b * 4096 * 512) + (size_t)h * 64;
#pragma unroll
    for (int i = 0; i < 8; ++i) {
        const int f = tid + 256 * i;
        const int t = f >> 4, e4 = f & 15;
        const float4 v = *(const float4*)(qb + (size_t)(c5 + 32 * t) * 512 + e4 * 4);
        tile[t][e4 * 4 + 0] = v.x;
        tile[t][e4 * 4 + 1] = v.y;
        tile[t][e4 * 4 + 2] = v.z;
        tile[t][e4 * 4 + 3] = v.w;
    }
    lds_barrier();

    const int wave = tid >> 6, lane = tid & 63;
    const int rl  = __brev(lane) >> 26;  // rev6(lane)
    const int r5c = __brev(c5) >> 27;    // rev5(c5)
    for (int cc = wave; cc < 32; cc += 4) {
        const int eo = cc >> 2, p = cc & 3;
        const int col0 = eo * 8 + 2 * p;
        float2* dst = T + ((size_t)((b * 8 + h) * 8 + eo)) * 16384 + (size_t)p * 4096
                        + (size_t)r5c * 128;
        float4 o;
        o.x = tile[rl][col0];      o.y = tile[rl][col0 + 1];
        o.z = tile[rl + 64][col0]; o.w = tile[rl + 64][col0 + 1];
        *(float4*)(dst + 2 * lane) = o;  // 16B/lane, contiguous 1KB run per (eo,p)
    }
}

// ---------------- FFT (3 x radix-16 passes) + fp16 spectrum store + score accumulation ---------
// 2048 blocks = (octet bi, half hh): planes 2hh, 2hh+1. LDS = z only (exactly 32 KB -> 5
// blocks/CU); ALL twiddles hoisted to registers before the plane loop (plane-invariant).
// fp16 spectrum layout (race-free across the 2-block split): half2 index of (plane p, bin) =
// bi*32768 + (p>>1)*8192 + (p&1)*4096 (+2048 for the odd signal) -- each block writes only
// into its own consumed float2 bytes [bi*128K + hh*64K, +32K).
__global__ __launch_bounds__(256) void k_fft(const float2* __restrict__ trig,
                                             float2* __restrict__ Xout,
                                             unsigned long long* __restrict__ score) {
    __shared__ float2 z[4096];    // 32 KB (swizzled indexing)

    const int tid = threadIdx.x;
    const int bi  = blockIdx.x >> 1;
    const int hh  = blockIdx.x & 1;

    // hoist pass-1 twiddles (j1 = tid&15) and pass-2 twiddles (j2 = tid) into registers
    const int j1 = tid & 15;
    float2 p1A, p1B, p1C, p1D, p2A, p2B, p2C, p2D;
    {
        float2 a = trig[j1 << 7], b = trig[j1 << 6], c = trig[j1 << 5], d = trig[j1 << 4];
        p1A = make_float2(a.x, -a.y); p1B = make_float2(b.x, -b.y);
        p1C = make_float2(c.x, -c.y); p1D = make_float2(d.x, -d.y);
    }
    {
        float2 a = trig[tid << 3], b = trig[tid << 2], c = trig[tid << 1], d = trig[tid];
        p2A = make_float2(a.x, -a.y); p2B = make_float2(b.x, -b.y);
        p2C = make_float2(c.x, -c.y); p2D = make_float2(d.x, -d.y);
    }

    float eaccr[8];
#pragma unroll
    for (int k = 0; k < 8; ++k) eaccr[k] = 0.f;

    const float2 ONE = make_float2(1.0f, 0.0f);
    const float2* base = Xout + (size_t)bi * 16384 + (size_t)hh * 8192;
    __half2* Xh = (__half2*)Xout;

    float4 pre[8];
#pragma unroll
    for (int g = 0; g < 8; ++g) pre[g] = *(const float4*)(base + 16 * tid + 2 * g);

#pragma unroll
    for (int pl = 0; pl < 2; ++pl) {
        float2 x[16];
#pragma unroll
        for (int g = 0; g < 8; ++g) {
            x[2 * g]     = make_float2(pre[g].x, pre[g].y);
            x[2 * g + 1] = make_float2(pre[g].z, pre[g].w);
        }
        if (pl == 0) {
            const float2* pn = base + 4096;
#pragma unroll
            for (int g = 0; g < 8; ++g) pre[g] = *(const float4*)(pn + 16 * tid + 2 * g);
        }

        // pass 0: stages 1-4 on 16 contiguous bit-reversed points, constant twiddles
        radix16(x, ONE, ONE, ONE, ONE);
        {
            const int i0 = 16 * tid;
#pragma unroll
            for (int s = 0; s < 8; ++s) {
                *(float4*)&z[ZI(i0 + 2 * s)] = make_float4(x[2 * s].x, x[2 * s].y,
                                                           x[2 * s + 1].x, x[2 * s + 1].y);
            }
        }
        lds_barrier();

        // pass 1: st=5, h=16
        {
            const int g = tid >> 4;
            const int i0 = (g << 8) + j1;
            int ad[16];
#pragma unroll
            for (int k = 0; k < 16; ++k) ad[k] = ZI(i0 + 16 * k);
#pragma unroll
            for (int k = 0; k < 16; ++k) x[k] = z[ad[k]];
            radix16(x, p1A, p1B, p1C, p1D);
#pragma unroll
            for (int k = 0; k < 16; ++k) z[ad[k]] = x[k];
        }
        lds_barrier();

        // pass 2: st=9, h=256
        {
            int ad[16];
#pragma unroll
            for (int k = 0; k < 16; ++k) ad[k] = ZI(tid + 256 * k);
#pragma unroll
            for (int k = 0; k < 16; ++k) x[k] = z[ad[k]];
            radix16(x, p2A, p2B, p2C, p2D);
#pragma unroll
            for (int k = 0; k < 16; ++k) z[ad[k]] = x[k];
        }
        lds_barrier();

        // unpack two real spectra; fp16 store (own consumed bytes); f32 energy accumulation
        {
            const size_t s0 = (size_t)bi * 32768 + (size_t)hh * 8192 + (size_t)pl * 4096;
#pragma unroll
            for (int k = 0; k < 8; ++k) {
                const int t = tid + 256 * k;
                const int m = t + 1;
                float2 Za = z[ZI(m)];
                float2 Zb = z[ZI(4096 - m)];
                float Xr0 = 0.5f * (Za.x + Zb.x);
                float Xi0 = 0.5f * (Za.y - Zb.y);
                float Xr1 = 0.5f * (Za.y + Zb.y);
                float Xi1 = 0.5f * (Zb.x - Za.x);
                Xh[s0 + t]        = __floats2half2_rn(Xr0, Xi0);
                Xh[s0 + 2048 + t] = __floats2half2_rn(Xr1, Xi1);
                eaccr[k] += Xr0 * Xr0 + Xi0 * Xi0 + Xr1 * Xr1 + Xi1 * Xi1;
            }
        }
        lds_barrier();
    }

#pragma unroll
    for (int k = 0; k < 8; ++k) {
        unsigned long long v = (unsigned long long)llrintf(eaccr[k] * 1048576.0f);  // 2^20
        atomicAdd(&score[tid + 256 * k], v);
    }
}

// ---------------- top-64, parallelized: 8 blocks x 256 threads -------------------------------
__global__ __launch_bounds__(256) void k_topk(const unsigned long long* __restrict__ score,
                                              int* __restrict__ idx) {
    __shared__ unsigned long long s[2048];
    const int tid = threadIdx.x;
    for (int t = tid; t < 2048; t += 256) s[t] = score[t];
    __syncthreads();

    const int t = blockIdx.x * 256 + tid;  // 0..2047
    const unsigned long long my = s[t];
    int rank = 0;
#pragma unroll 8
    for (int u = 0; u < 2048; ++u) {
        unsigned long long o = s[u];
        rank += (int)((o > my) || (o == my && u < t));
    }
    if (rank < 64) idx[rank] = t + 1;  // store frequency index m
}

// ---------------- gather + projection -> fp16 Bt for the MFMA synth ---------------------------
// Spectrum layout: half2 idx of (sig, bin) with p = (sig>>1)&3:
//   (sig>>3)*32768 + (p>>1)*8192 + (p&1)*4096 + (sig&1)*2048 + bin.
__global__ __launch_bounds__(256) void k_proj(const __half2* __restrict__ Xh,
                                              const float* __restrict__ wr,
                                              const float* __restrict__ wi,
                                              const int* __restrict__ idx,
                                              _Float16* __restrict__ Yt) {
    __shared__ __align__(16) float2 xs[4 * 64];  // [b_loc][e]  2 KB
    __shared__ float  wrs[64 * 64];              // [e][f] 16 KB
    __shared__ float  wis[64 * 64];              // 16 KB

    const int tid = threadIdx.x;
    const int j  = blockIdx.x >> 5;
    const int h  = (blockIdx.x >> 2) & 7;
    const int bq = blockIdx.x & 3;
    const int m = idx[j];

    {
        const int bl = tid >> 6, e = tid & 63;
        const int sig = (((bq * 4 + bl) * 8 + h) * 64 + e);
        const int p2 = (sig >> 1) & 3;
        const size_t xi = (size_t)(sig >> 3) * 32768 + (size_t)(p2 >> 1) * 8192
                        + (size_t)(p2 & 1) * 4096 + (size_t)(sig & 1) * 2048 + (size_t)(m - 1);
        xs[tid] = __half22float2(Xh[xi]);
    }
    const float* wrb = wr + ((size_t)(j * 8 + h)) * 4096;
    const float* wib = wi + ((size_t)(j * 8 + h)) * 4096;
#pragma unroll
    for (int i = 0; i < 16; ++i) {
        const int t = tid + 256 * i;
        wrs[t] = wrb[t];
        wis[t] = wib[t];
    }
    lds_barrier();

    const int bl = tid >> 6;   // 0..3
    const int f  = tid & 63;   // 0..63
    const float2* xrow = &xs[bl * 64];
    float yr = 0.f, yi = 0.f;
#pragma unroll
    for (int e = 0; e < 64; e += 4) {
        const float4 xa = *(const float4*)&xrow[e];
        const float4 xb = *(const float4*)&xrow[e + 2];
        const float2 xv[4] = {make_float2(xa.x, xa.y), make_float2(xa.z, xa.w),
                              make_float2(xb.x, xb.y), make_float2(xb.z, xb.w)};
#pragma unroll
        for (int d = 0; d < 4; ++d) {
            const float a = wrs[(e + d) * 64 + f], cc = wis[(e + d) * 64 + f];
            yr = __builtin_fmaf(xv[d].x, a, yr); yr = __builtin_fmaf(-xv[d].y, cc, yr);
            yi = __builtin_fmaf(xv[d].x, cc, yi); yi = __builtin_fmaf( xv[d].y, a, yi);
        }
    }
    const int b  = bq * 4 + bl;
    const int hf = h * 64 + f;
    _Float16* yt = Yt + ((size_t)b * 512 + (size_t)hf) * 128;
    yt[j]      = (_Float16)(j == 0 ? 0.5f * yr : yr);
    yt[64 + j] = (_Float16)yi;
}

// ---------------- MFMA synthesis: out[b, l, hf] = (2/N) * sum_k Af[l,k] * Yt[b,hf,k] ----------
__global__ __launch_bounds__(256) void k_synth(const _Float16* __restrict__ Af,
                                               const _Float16* __restrict__ Yt,
                                               float* __restrict__ out) {
    const int tid  = threadIdx.x;
    const int wv   = tid >> 6;
    const int lane = tid & 63;
    const int bi   = blockIdx.x;
    const int b    = bi >> 8;         // 16
    const int ng   = (bi >> 6) & 3;   // 4
    const int lt   = bi & 63;         // 64

    const int l0 = lt * 64;
    const int n0 = ng * 128 + wv * 32;

    const int row = lane & 15;        // A-row / B-col / C-col
    const int kb  = lane >> 4;        // k-block 0..3

    f32x4 acc[4][2] = {};

    const _Float16* Ab = Af + (size_t)l0 * 128;
    const _Float16* Bb = Yt + (size_t)b * 512 * 128 + (size_t)n0 * 128;

#pragma unroll
    for (int k0 = 0; k0 < 128; k0 += 32) {
        f16x8 a[4], bf[2];
#pragma unroll
        for (int mt = 0; mt < 4; ++mt)
            a[mt] = *(const f16x8*)(Ab + (size_t)(mt * 16 + row) * 128 + k0 + kb * 8);
#pragma unroll
        for (int nt = 0; nt < 2; ++nt)
            bf[nt] = *(const f16x8*)(Bb + (size_t)(nt * 16 + row) * 128 + k0 + kb * 8);
#pragma unroll
        for (int mt = 0; mt < 4; ++mt)
#pragma unroll
            for (int nt = 0; nt < 2; ++nt)
                acc[mt][nt] = __builtin_amdgcn_mfma_f32_16x16x32_f16(a[mt], bf[nt],
                                                                     acc[mt][nt], 0, 0, 0);
    }

    const float s = 2.0f / 4096.0f;
#pragma unroll
    for (int mt = 0; mt < 4; ++mt) {
#pragma unroll
        for (int nt = 0; nt < 2; ++nt) {
            const int col = n0 + nt * 16 + row;  // hf
#pragma unroll
            for (int r = 0; r < 4; ++r) {
                const int mrow = mt * 16 + kb * 4 + r;
                out[((size_t)(b * 4096 + l0 + mrow)) * 512 + col] = acc[mt][nt][r] * s;
            }
        }
    }
}

// ---------------- launch ----------------
extern "C" void kernel_launch(void* const* d_in, const int* in_sizes, int n_in,
                              void* d_out, int out_size, void* d_ws, size_t ws_size,
                              hipStream_t stream) {
    const float* q  = (const float*)d_in[0];
    const float* wr = (const float*)d_in[3];
    const float* wi = (const float*)d_in[4];

    char* ws = (char*)d_ws;
    float2*             trig  = (float2*)(ws + 0);                  // 32 KB
    unsigned long long* score = (unsigned long long*)(ws + 32768);  // 16 KB
    int*                idx   = (int*)(ws + 49152);                 // 256 B
    _Float16*           Af    = (_Float16*)(ws + 65536);            // 1 MB
    _Float16*           Yt    = (_Float16*)(ws + 65536 + 1048576);  // 2 MB

    // d_out triples as: transposed-q scratch T -> fp16 spectrum (in-place, per-octet regions)
    // -> final output.
    float2* Xs = (float2*)d_out;

    k_init<<<2064, 256, 0, stream>>>(trig, score, Af);   // trig + score + Af in one dispatch
    k_xpose<<<4096, 256, 0, stream>>>(q, Xs);            // (b:16, h:8, c5:32), 128-row tiles
    k_fft<<<2048, 256, 0, stream>>>(trig, Xs, score);    // (octet, half): 2 planes/block
    k_topk<<<8, 256, 0, stream>>>(score, idx);           // 2048 candidates, 1/thread
    k_proj<<<2048, 256, 0, stream>>>((const __half2*)Xs, wr, wi, idx, Yt);  // -> fp16 Bt
    k_synth<<<4096, 256, 0, stream>>>(Af, Yt, (float*)d_out);               // MFMA GEMM
}

// Round 22
// 228.874 us; speedup vs baseline: 1.0598x; 1.0598x over previous
//
#include <hip/hip_runtime.h>
#include <hip/hip_fp16.h>

// Problem constants: B=16, L=4096, H=8, E=64, K=64, F=2049 (rfft bins)
// Only bins m in [1,2048] matter (bin 0 excluded from top-k; out_ft uses slots 0..63).

#define NTHREADS 256

typedef _Float16 f16x8 __attribute__((ext_vector_type(8)));
typedef float    f32x4 __attribute__((ext_vector_type(4)));

// LDS-only barrier: drains LDS ops (lgkmcnt) but leaves global loads/stores in flight.
__device__ inline void lds_barrier() {
    asm volatile("s_waitcnt lgkmcnt(0)" ::: "memory");
    __builtin_amdgcn_s_barrier();
}

// LDS swizzle for the FFT working array: flips bits 1-3 by bits 4-6 (bijective, disjoint).
// Preserves bit 0, so (2s, 2s+1) pairs stay contiguous -> b128 pair stores are legal.
#define ZI(i) ((i) ^ ((((i) >> 4) & 7) << 1))

__device__ inline float2 f2add(float2 a, float2 b) { return make_float2(a.x + b.x, a.y + b.y); }
__device__ inline float2 f2sub(float2 a, float2 b) { return make_float2(a.x - b.x, a.y - b.y); }
// complex mul, exactly 4 VALU (mul, fma, mul, fma)
__device__ inline float2 cmulf(float2 a, float2 b) {
    return make_float2(__builtin_fmaf(a.x, b.x, -(a.y * b.y)),
                       __builtin_fmaf(a.x, b.y,  a.y * b.x));
}

// radix-16 DIT butterfly on 16 points (4 stages st..st+3 in registers).
__device__ inline void radix16(float2 x[16], float2 tA, float2 tB, float2 tC, float2 tD) {
#pragma unroll
    for (int q = 0; q < 8; ++q) {
        float2 v = cmulf(tA, x[2 * q + 1]);
        float2 u = x[2 * q];
        x[2 * q]     = f2add(u, v);
        x[2 * q + 1] = f2sub(u, v);
    }
    {
        float2 tB1 = make_float2(tB.y, -tB.x);
#pragma unroll
        for (int q = 0; q < 4; ++q) {
            {
                float2 v = cmulf(tB, x[4 * q + 2]);
                float2 u = x[4 * q];
                x[4 * q]     = f2add(u, v);
                x[4 * q + 2] = f2sub(u, v);
            }
            {
                float2 v = cmulf(tB1, x[4 * q + 3]);
                float2 u = x[4 * q + 1];
                x[4 * q + 1] = f2add(u, v);
                x[4 * q + 3] = f2sub(u, v);
            }
        }
    }
    {
        const float C = 0.70710678118654752f;
        float2 w0 = tC;
        float2 w1 = cmulf(tC, make_float2(C, -C));
        float2 w2 = make_float2(tC.y, -tC.x);
        float2 w3 = cmulf(tC, make_float2(-C, -C));
#pragma unroll
        for (int q = 0; q < 2; ++q) {
            float2 ws[4] = {w0, w1, w2, w3};
#pragma unroll
            for (int r = 0; r < 4; ++r) {
                float2 v = cmulf(ws[r], x[8 * q + r + 4]);
                float2 u = x[8 * q + r];
                x[8 * q + r]     = f2add(u, v);
                x[8 * q + r + 4] = f2sub(u, v);
            }
        }
    }
    {
        const float C  = 0.70710678118654752f;
        const float C1 = 0.92387953251128676f;  // cos(pi/8)
        const float S1 = 0.38268343236508977f;  // sin(pi/8)
        float2 wD[8];
        wD[0] = tD;
        wD[1] = cmulf(tD, make_float2(C1, -S1));
        wD[2] = cmulf(tD, make_float2(C, -C));
        wD[3] = cmulf(tD, make_float2(S1, -C1));
        wD[4] = make_float2(tD.y, -tD.x);
        wD[5] = cmulf(tD, make_float2(-S1, -C1));
        wD[6] = cmulf(tD, make_float2(-C, -C));
        wD[7] = cmulf(tD, make_float2(-C1, -S1));
#pragma unroll
        for (int r = 0; r < 8; ++r) {
            float2 v = cmulf(wD[r], x[r + 8]);
            float2 u = x[r];
            x[r]     = f2add(u, v);
            x[r + 8] = f2sub(u, v);
        }
    }
}

// ---------------- init: trig (f64-accurate) + score zeroing + fp16 Af matrix ------------------
__global__ __launch_bounds__(256) void k_init(float2* __restrict__ trig,
                                              unsigned long long* __restrict__ score,
                                              _Float16* __restrict__ Af) {
    const int g = blockIdx.x * 256 + threadIdx.x;
    if (g < 4096) {
        double th = (6.283185307179586476925286766559 * (double)g) / 4096.0;
        trig[g] = make_float2((float)cos(th), (float)sin(th));
        if (g < 2048) score[g] = 0ULL;
    } else {
        const int gid = g - 4096;           // 0 .. 524287
        const int l = gid >> 7, k = gid & 127;
        const int kk = (k < 64) ? k : k - 64;
        const int ph = (kk * l) & 4095;
        const float th = 1.5339807878856412e-3f * (float)ph;  // 2*pi/4096
        float v = (k < 64) ? __cosf(th) : -__sinf(th);
        Af[gid] = (_Float16)v;
    }
}

// ---------------- transpose + bit-reversal: q[b,l,h,e] -> T[(b,h,eo)][p][j] (float2) -----------
__global__ __launch_bounds__(256) void k_xpose(const float* __restrict__ q,
                                               float2* __restrict__ T) {
    __shared__ float tile[128][65];  // 33 KB, padded (+1)

    const int tid = threadIdx.x;
    const int bi  = blockIdx.x;
    const int b   = bi >> 8;
    const int h   = (bi >> 5) & 7;
    const int c5  = bi & 31;

    const float* qb = q + ((size_t)b * 4096 * 512) + (size_t)h * 64;
#pragma unroll
    for (int i = 0; i < 8; ++i) {
        const int f = tid + 256 * i;
        const int t = f >> 4, e4 = f & 15;
        const float4 v = *(const float4*)(qb + (size_t)(c5 + 32 * t) * 512 + e4 * 4);
        tile[t][e4 * 4 + 0] = v.x;
        tile[t][e4 * 4 + 1] = v.y;
        tile[t][e4 * 4 + 2] = v.z;
        tile[t][e4 * 4 + 3] = v.w;
    }
    lds_barrier();

    const int wave = tid >> 6, lane = tid & 63;
    const int rl  = __brev(lane) >> 26;  // rev6(lane)
    const int r5c = __brev(c5) >> 27;    // rev5(c5)
    for (int cc = wave; cc < 32; cc += 4) {
        const int eo = cc >> 2, p = cc & 3;
        const int col0 = eo * 8 + 2 * p;
        float2* dst = T + ((size_t)((b * 8 + h) * 8 + eo)) * 16384 + (size_t)p * 4096
                        + (size_t)r5c * 128;
        float4 o;
        o.x = tile[rl][col0];      o.y = tile[rl][col0 + 1];
        o.z = tile[rl + 64][col0]; o.w = tile[rl + 64][col0 + 1];
        *(float4*)(dst + 2 * lane) = o;  // 16B/lane, contiguous 1KB run per (eo,p)
    }
}

// ---------------- FFT (3 x radix-16 passes) + fp16 spectrum store + score accumulation ---------
// R20 structure: 1024 blocks, 4 planes/block, register prefetch, ctw4 LDS quads for pass 1,
// pass-2 twiddles from global trig (L1-hot). fp16 spectrum in the block's own 128KB region:
// half2 index bi*32768 + p*4096 (+2048) -- covers only already-consumed float2 bytes, never
// the in-flight prefetch of plane p+1.
__global__ __launch_bounds__(256) void k_fft(const float2* __restrict__ trig,
                                             float2* __restrict__ Xout,
                                             unsigned long long* __restrict__ score) {
    __shared__ float2 z[4096];    // 32 KB (swizzled indexing)
    __shared__ float2 ctw4[80];   // pass1 quads, stride-5 layout (conflict-free mod 16)

    const int tid = threadIdx.x;
    const int bi  = blockIdx.x;

    if (tid < 64) {
        const int j = tid >> 2, qq = tid & 3;
        float2 a = trig[j << (7 - qq)];
        ctw4[5 * j + qq] = make_float2(a.x, -a.y);
    }

    float eaccr[8];
#pragma unroll
    for (int k = 0; k < 8; ++k) eaccr[k] = 0.f;

    const float2 ONE = make_float2(1.0f, 0.0f);
    const float2* base = Xout + (size_t)bi * 16384;
    __half2* Xh = (__half2*)Xout;

    float4 pre[8];
#pragma unroll
    for (int g = 0; g < 8; ++g) pre[g] = *(const float4*)(base + 16 * tid + 2 * g);
    lds_barrier();  // ctw4 ready (prefetch loads stay in flight)

    for (int p = 0; p < 4; ++p) {
        float2 x[16];
#pragma unroll
        for (int g = 0; g < 8; ++g) {
            x[2 * g]     = make_float2(pre[g].x, pre[g].y);
            x[2 * g + 1] = make_float2(pre[g].z, pre[g].w);
        }
        if (p < 3) {
            const float2* pn = base + (size_t)(p + 1) * 4096;
#pragma unroll
            for (int g = 0; g < 8; ++g) pre[g] = *(const float4*)(pn + 16 * tid + 2 * g);
        }

        radix16(x, ONE, ONE, ONE, ONE);
        {
            const int i0 = 16 * tid;
#pragma unroll
            for (int s = 0; s < 8; ++s) {
                *(float4*)&z[ZI(i0 + 2 * s)] = make_float4(x[2 * s].x, x[2 * s].y,
                                                           x[2 * s + 1].x, x[2 * s + 1].y);
            }
        }
        lds_barrier();

        // pass 1: st=5, h=16
        {
            const int j = tid & 15;
            const int g = tid >> 4;
            const int i0 = (g << 8) + j;
            int ad[16];
#pragma unroll
            for (int k = 0; k < 16; ++k) ad[k] = ZI(i0 + 16 * k);
#pragma unroll
            for (int k = 0; k < 16; ++k) x[k] = z[ad[k]];
            const float2 tA = ctw4[5 * j + 0];
            const float2 tB = ctw4[5 * j + 1];
            const float2 tC = ctw4[5 * j + 2];
            const float2 tD = ctw4[5 * j + 3];
            radix16(x, tA, tB, tC, tD);
#pragma unroll
            for (int k = 0; k < 16; ++k) z[ad[k]] = x[k];
        }
        lds_barrier();

        // pass 2: st=9, h=256
        {
            const int j = tid;
            int ad[16];
#pragma unroll
            for (int k = 0; k < 16; ++k) ad[k] = ZI(j + 256 * k);
#pragma unroll
            for (int k = 0; k < 16; ++k) x[k] = z[ad[k]];
            float2 a = trig[j << 3], b2 = trig[j << 2], c = trig[j << 1], d = trig[j];
            const float2 tA = make_float2(a.x, -a.y);
            const float2 tB = make_float2(b2.x, -b2.y);
            const float2 tC = make_float2(c.x, -c.y);
            const float2 tD = make_float2(d.x, -d.y);
            radix16(x, tA, tB, tC, tD);
#pragma unroll
            for (int k = 0; k < 16; ++k) z[ad[k]] = x[k];
        }
        lds_barrier();

        // unpack two real spectra; fp16 store (own-region layout); f32 energy accumulation
        {
            const size_t s0 = (size_t)bi * 32768 + (size_t)p * 4096;  // half2 idx, own 128KB region
#pragma unroll
            for (int k = 0; k < 8; ++k) {
                const int t = tid + 256 * k;
                const int m = t + 1;
                float2 Za = z[ZI(m)];
                float2 Zb = z[ZI(4096 - m)];
                float Xr0 = 0.5f * (Za.x + Zb.x);
                float Xi0 = 0.5f * (Za.y - Zb.y);
                float Xr1 = 0.5f * (Za.y + Zb.y);
                float Xi1 = 0.5f * (Zb.x - Za.x);
                Xh[s0 + t]        = __floats2half2_rn(Xr0, Xi0);
                Xh[s0 + 2048 + t] = __floats2half2_rn(Xr1, Xi1);
                eaccr[k] += Xr0 * Xr0 + Xi0 * Xi0 + Xr1 * Xr1 + Xi1 * Xi1;
            }
        }
        lds_barrier();
    }

#pragma unroll
    for (int k = 0; k < 8; ++k) {
        unsigned long long v = (unsigned long long)llrintf(eaccr[k] * 1048576.0f);  // 2^20
        atomicAdd(&score[tid + 256 * k], v);
    }
}

// ---------------- top-64, parallelized: 8 blocks x 256 threads -------------------------------
__global__ __launch_bounds__(256) void k_topk(const unsigned long long* __restrict__ score,
                                              int* __restrict__ idx) {
    __shared__ unsigned long long s[2048];
    const int tid = threadIdx.x;
    for (int t = tid; t < 2048; t += 256) s[t] = score[t];
    __syncthreads();

    const int t = blockIdx.x * 256 + tid;  // 0..2047
    const unsigned long long my = s[t];
    int rank = 0;
#pragma unroll 8
    for (int u = 0; u < 2048; ++u) {
        unsigned long long o = s[u];
        rank += (int)((o > my) || (o == my && u < t));
    }
    if (rank < 64) idx[rank] = t + 1;  // store frequency index m
}

// ---------------- gather + projection -> fp16 Bt for the MFMA synth ---------------------------
// Spectrum layout (per-octet regions): half2 idx of (sig, bin) =
//   (sig>>3)*32768 + ((sig>>1)&3)*4096 + (sig&1)*2048 + bin.
__global__ __launch_bounds__(256) void k_proj(const __half2* __restrict__ Xh,
                                              const float* __restrict__ wr,
                                              const float* __restrict__ wi,
                                              const int* __restrict__ idx,
                                              _Float16* __restrict__ Yt) {
    __shared__ __align__(16) float2 xs[4 * 64];  // [b_loc][e]  2 KB
    __shared__ float  wrs[64 * 64];              // [e][f] 16 KB
    __shared__ float  wis[64 * 64];              // 16 KB

    const int tid = threadIdx.x;
    const int j  = blockIdx.x >> 5;
    const int h  = (blockIdx.x >> 2) & 7;
    const int bq = blockIdx.x & 3;
    const int m = idx[j];

    {
        const int bl = tid >> 6, e = tid & 63;
        const int sig = (((bq * 4 + bl) * 8 + h) * 64 + e);
        const size_t xi = (size_t)(sig >> 3) * 32768 + (size_t)((sig >> 1) & 3) * 4096
                        + (size_t)(sig & 1) * 2048 + (size_t)(m - 1);
        xs[tid] = __half22float2(Xh[xi]);
    }
    const float* wrb = wr + ((size_t)(j * 8 + h)) * 4096;
    const float* wib = wi + ((size_t)(j * 8 + h)) * 4096;
#pragma unroll
    for (int i = 0; i < 16; ++i) {
        const int t = tid + 256 * i;
        wrs[t] = wrb[t];
        wis[t] = wib[t];
    }
    lds_barrier();

    const int bl = tid >> 6;   // 0..3
    const int f  = tid & 63;   // 0..63
    const float2* xrow = &xs[bl * 64];
    float yr = 0.f, yi = 0.f;
#pragma unroll
    for (int e = 0; e < 64; e += 4) {
        const float4 xa = *(const float4*)&xrow[e];
        const float4 xb = *(const float4*)&xrow[e + 2];
        const float2 xv[4] = {make_float2(xa.x, xa.y), make_float2(xa.z, xa.w),
                              make_float2(xb.x, xb.y), make_float2(xb.z, xb.w)};
#pragma unroll
        for (int d = 0; d < 4; ++d) {
            const float a = wrs[(e + d) * 64 + f], cc = wis[(e + d) * 64 + f];
            yr = __builtin_fmaf(xv[d].x, a, yr); yr = __builtin_fmaf(-xv[d].y, cc, yr);
            yi = __builtin_fmaf(xv[d].x, cc, yi); yi = __builtin_fmaf( xv[d].y, a, yi);
        }
    }
    const int b  = bq * 4 + bl;
    const int hf = h * 64 + f;
    _Float16* yt = Yt + ((size_t)b * 512 + (size_t)hf) * 128;
    yt[j]      = (_Float16)(j == 0 ? 0.5f * yr : yr);
    yt[64 + j] = (_Float16)yi;
}

// ---------------- MFMA synthesis: out[b, l, hf] = (2/N) * sum_k Af[l,k] * Yt[b,hf,k] ----------
__global__ __launch_bounds__(256) void k_synth(const _Float16* __restrict__ Af,
                                               const _Float16* __restrict__ Yt,
                                               float* __restrict__ out) {
    const int tid  = threadIdx.x;
    const int wv   = tid >> 6;
    const int lane = tid & 63;
    const int bi   = blockIdx.x;
    const int b    = bi >> 8;         // 16
    const int ng   = (bi >> 6) & 3;   // 4
    const int lt   = bi & 63;         // 64

    const int l0 = lt * 64;
    const int n0 = ng * 128 + wv * 32;

    const int row = lane & 15;        // A-row / B-col / C-col
    const int kb  = lane >> 4;        // k-block 0..3

    f32x4 acc[4][2] = {};

    const _Float16* Ab = Af + (size_t)l0 * 128;
    const _Float16* Bb = Yt + (size_t)b * 512 * 128 + (size_t)n0 * 128;

#pragma unroll
    for (int k0 = 0; k0 < 128; k0 += 32) {
        f16x8 a[4], bf[2];
#pragma unroll
        for (int mt = 0; mt < 4; ++mt)
            a[mt] = *(const f16x8*)(Ab + (size_t)(mt * 16 + row) * 128 + k0 + kb * 8);
#pragma unroll
        for (int nt = 0; nt < 2; ++nt)
            bf[nt] = *(const f16x8*)(Bb + (size_t)(nt * 16 + row) * 128 + k0 + kb * 8);
#pragma unroll
        for (int mt = 0; mt < 4; ++mt)
#pragma unroll
            for (int nt = 0; nt < 2; ++nt)
                acc[mt][nt] = __builtin_amdgcn_mfma_f32_16x16x32_f16(a[mt], bf[nt],
                                                                     acc[mt][nt], 0, 0, 0);
    }

    const float s = 2.0f / 4096.0f;
#pragma unroll
    for (int mt = 0; mt < 4; ++mt) {
#pragma unroll
        for (int nt = 0; nt < 2; ++nt) {
            const int col = n0 + nt * 16 + row;  // hf
#pragma unroll
            for (int r = 0; r < 4; ++r) {
                const int mrow = mt * 16 + kb * 4 + r;
                out[((size_t)(b * 4096 + l0 + mrow)) * 512 + col] = acc[mt][nt][r] * s;
            }
        }
    }
}

// ---------------- launch ----------------
extern "C" void kernel_launch(void* const* d_in, const int* in_sizes, int n_in,
                              void* d_out, int out_size, void* d_ws, size_t ws_size,
                              hipStream_t stream) {
    const float* q  = (const float*)d_in[0];
    const float* wr = (const float*)d_in[3];
    const float* wi = (const float*)d_in[4];

    char* ws = (char*)d_ws;
    float2*             trig  = (float2*)(ws + 0);                  // 32 KB
    unsigned long long* score = (unsigned long long*)(ws + 32768);  // 16 KB
    int*                idx   = (int*)(ws + 49152);                 // 256 B
    _Float16*           Af    = (_Float16*)(ws + 65536);            // 1 MB
    _Float16*           Yt    = (_Float16*)(ws + 65536 + 1048576);  // 2 MB

    // d_out triples as: transposed-q scratch T -> fp16 spectrum (in-place, per-octet regions)
    // -> final output.
    float2* Xs = (float2*)d_out;

    k_init<<<2064, 256, 0, stream>>>(trig, score, Af);   // trig + score + Af in one dispatch
    k_xpose<<<4096, 256, 0, stream>>>(q, Xs);            // (b:16, h:8, c5:32), 128-row tiles
    k_fft<<<1024, 256, 0, stream>>>(trig, Xs, score);    // R20: 4 planes/block, prefetch
    k_topk<<<8, 256, 0, stream>>>(score, idx);           // 2048 candidates, 1/thread
    k_proj<<<2048, 256, 0, stream>>>((const __half2*)Xs, wr, wi, idx, Yt);  // -> fp16 Bt
    k_synth<<<4096, 256, 0, stream>>>(Af, Yt, (float*)d_out);               // MFMA GEMM
}

// Round 23
// 227.654 us; speedup vs baseline: 1.0654x; 1.0054x over previous
//
#include <hip/hip_runtime.h>
#include <hip/hip_fp16.h>

// Problem constants: B=16, L=4096, H=8, E=64, K=64, F=2049 (rfft bins)
// Only bins m in [1,2048] matter (bin 0 excluded from top-k; out_ft uses slots 0..63).

#define NTHREADS 256

typedef _Float16 f16x8 __attribute__((ext_vector_type(8)));
typedef float    f32x4 __attribute__((ext_vector_type(4)));

// LDS-only barrier: drains LDS ops (lgkmcnt) but leaves global loads/stores in flight.
__device__ inline void lds_barrier() {
    asm volatile("s_waitcnt lgkmcnt(0)" ::: "memory");
    __builtin_amdgcn_s_barrier();
}

// LDS swizzle for the FFT working array: flips bits 1-3 by bits 4-6 (bijective, disjoint).
// Preserves bit 0, so (2s, 2s+1) pairs stay contiguous -> b128 pair stores are legal.
#define ZI(i) ((i) ^ ((((i) >> 4) & 7) << 1))

__device__ inline float2 f2add(float2 a, float2 b) { return make_float2(a.x + b.x, a.y + b.y); }
__device__ inline float2 f2sub(float2 a, float2 b) { return make_float2(a.x - b.x, a.y - b.y); }
// complex mul, exactly 4 VALU (mul, fma, mul, fma)
__device__ inline float2 cmulf(float2 a, float2 b) {
    return make_float2(__builtin_fmaf(a.x, b.x, -(a.y * b.y)),
                       __builtin_fmaf(a.x, b.y,  a.y * b.x));
}

// radix-16 DIT butterfly on 16 points (4 stages st..st+3 in registers).
__device__ inline void radix16(float2 x[16], float2 tA, float2 tB, float2 tC, float2 tD) {
#pragma unroll
    for (int q = 0; q < 8; ++q) {
        float2 v = cmulf(tA, x[2 * q + 1]);
        float2 u = x[2 * q];
        x[2 * q]     = f2add(u, v);
        x[2 * q + 1] = f2sub(u, v);
    }
    {
        float2 tB1 = make_float2(tB.y, -tB.x);
#pragma unroll
        for (int q = 0; q < 4; ++q) {
            {
                float2 v = cmulf(tB, x[4 * q + 2]);
                float2 u = x[4 * q];
                x[4 * q]     = f2add(u, v);
                x[4 * q + 2] = f2sub(u, v);
            }
            {
                float2 v = cmulf(tB1, x[4 * q + 3]);
                float2 u = x[4 * q + 1];
                x[4 * q + 1] = f2add(u, v);
                x[4 * q + 3] = f2sub(u, v);
            }
        }
    }
    {
        const float C = 0.70710678118654752f;
        float2 w0 = tC;
        float2 w1 = cmulf(tC, make_float2(C, -C));
        float2 w2 = make_float2(tC.y, -tC.x);
        float2 w3 = cmulf(tC, make_float2(-C, -C));
#pragma unroll
        for (int q = 0; q < 2; ++q) {
            float2 ws[4] = {w0, w1, w2, w3};
#pragma unroll
            for (int r = 0; r < 4; ++r) {
                float2 v = cmulf(ws[r], x[8 * q + r + 4]);
                float2 u = x[8 * q + r];
                x[8 * q + r]     = f2add(u, v);
                x[8 * q + r + 4] = f2sub(u, v);
            }
        }
    }
    {
        const float C  = 0.70710678118654752f;
        const float C1 = 0.92387953251128676f;  // cos(pi/8)
        const float S1 = 0.38268343236508977f;  // sin(pi/8)
        float2 wD[8];
        wD[0] = tD;
        wD[1] = cmulf(tD, make_float2(C1, -S1));
        wD[2] = cmulf(tD, make_float2(C, -C));
        wD[3] = cmulf(tD, make_float2(S1, -C1));
        wD[4] = make_float2(tD.y, -tD.x);
        wD[5] = cmulf(tD, make_float2(-S1, -C1));
        wD[6] = cmulf(tD, make_float2(-C, -C));
        wD[7] = cmulf(tD, make_float2(-C1, -S1));
#pragma unroll
        for (int r = 0; r < 8; ++r) {
            float2 v = cmulf(wD[r], x[r + 8]);
            float2 u = x[r];
            x[r]     = f2add(u, v);
            x[r + 8] = f2sub(u, v);
        }
    }
}

// ---------------- init: trig (f64-accurate) + score zeroing + fp16 Af matrix ------------------
__global__ __launch_bounds__(256) void k_init(float2* __restrict__ trig,
                                              unsigned long long* __restrict__ score,
                                              _Float16* __restrict__ Af) {
    const int g = blockIdx.x * 256 + threadIdx.x;
    if (g < 4096) {
        double th = (6.283185307179586476925286766559 * (double)g) / 4096.0;
        trig[g] = make_float2((float)cos(th), (float)sin(th));
        if (g < 2048) score[g] = 0ULL;
    } else {
        const int gid = g - 4096;           // 0 .. 524287
        const int l = gid >> 7, k = gid & 127;
        const int kk = (k < 64) ? k : k - 64;
        const int ph = (kk * l) & 4095;
        const float th = 1.5339807878856412e-3f * (float)ph;  // 2*pi/4096
        float v = (k < 64) ? __cosf(th) : -__sinf(th);
        Af[gid] = (_Float16)v;
    }
}

// ---------------- transpose + bit-reversal: q[b,l,h,e] -> T[(b,h,eo)][p][j] (float2) -----------
// 64-row tiles (16.6 KB LDS -> 8 blocks/CU, wave-cap-limited occupancy). Block (b:16, h:8,
// c6:64): rows l = c6 + 64t (t=0..63). rev12(c6 + 64t) = rev6(c6)*64 + rev6(t): destination
// runs are contiguous 64-float2 (512 B) blocks. Within a run, j'-pair (2m,2m+1) comes from
// tile rows (rev5(m), rev5(m)+32); each wave stores two (eo,p) combos per iteration.
__global__ __launch_bounds__(256) void k_xpose(const float* __restrict__ q,
                                               float2* __restrict__ T) {
    __shared__ float tile[64][65];  // 16.6 KB, padded (+1)

    const int tid = threadIdx.x;
    const int bi  = blockIdx.x;
    const int b   = bi >> 9;         // 16
    const int h   = (bi >> 6) & 7;   // 8
    const int c6  = bi & 63;         // 64

    const float* qb = q + ((size_t)b * 4096 * 512) + (size_t)h * 64;
#pragma unroll
    for (int i = 0; i < 4; ++i) {
        const int f = tid + 256 * i;
        const int t = f >> 4, e4 = f & 15;
        const float4 v = *(const float4*)(qb + (size_t)(c6 + 64 * t) * 512 + e4 * 4);
        tile[t][e4 * 4 + 0] = v.x;
        tile[t][e4 * 4 + 1] = v.y;
        tile[t][e4 * 4 + 2] = v.z;
        tile[t][e4 * 4 + 3] = v.w;
    }
    lds_barrier();

    const int wave = tid >> 6, lane = tid & 63;
    const int half = lane >> 5;          // 0/1: which combo of the pair
    const int m    = lane & 31;          // float4 slot within the 64-float2 run
    const int rm   = __brev(m) >> 27;    // rev5(m)
    const int r6c  = __brev(c6) >> 26;   // rev6(c6)
#pragma unroll
    for (int it = 0; it < 4; ++it) {
        const int cc = wave * 8 + it * 2 + half;  // 0..31
        const int eo = cc >> 2, p = cc & 3;
        const int col0 = eo * 8 + 2 * p;
        float2* dst = T + ((size_t)((b * 8 + h) * 8 + eo)) * 16384 + (size_t)p * 4096
                        + (size_t)r6c * 64;
        float4 o;
        o.x = tile[rm][col0];      o.y = tile[rm][col0 + 1];
        o.z = tile[rm + 32][col0]; o.w = tile[rm + 32][col0 + 1];
        *(float4*)(dst + 2 * m) = o;  // 16B/lane, 512B runs, two combos per wave-iteration
    }
}

// ---------------- FFT (3 x radix-16 passes) + fp16 spectrum store + score accumulation ---------
// R20 structure: 1024 blocks, 4 planes/block, register prefetch, ctw4 LDS quads for pass 1,
// pass-2 twiddles from global trig (L1-hot). fp16 spectrum in the block's own 128KB region:
// half2 index bi*32768 + p*4096 (+2048) -- covers only already-consumed float2 bytes, never
// the in-flight prefetch of plane p+1.
__global__ __launch_bounds__(256) void k_fft(const float2* __restrict__ trig,
                                             float2* __restrict__ Xout,
                                             unsigned long long* __restrict__ score) {
    __shared__ float2 z[4096];    // 32 KB (swizzled indexing)
    __shared__ float2 ctw4[80];   // pass1 quads, stride-5 layout (conflict-free mod 16)

    const int tid = threadIdx.x;
    const int bi  = blockIdx.x;

    if (tid < 64) {
        const int j = tid >> 2, qq = tid & 3;
        float2 a = trig[j << (7 - qq)];
        ctw4[5 * j + qq] = make_float2(a.x, -a.y);
    }

    float eaccr[8];
#pragma unroll
    for (int k = 0; k < 8; ++k) eaccr[k] = 0.f;

    const float2 ONE = make_float2(1.0f, 0.0f);
    const float2* base = Xout + (size_t)bi * 16384;
    __half2* Xh = (__half2*)Xout;

    float4 pre[8];
#pragma unroll
    for (int g = 0; g < 8; ++g) pre[g] = *(const float4*)(base + 16 * tid + 2 * g);
    lds_barrier();  // ctw4 ready (prefetch loads stay in flight)

    for (int p = 0; p < 4; ++p) {
        float2 x[16];
#pragma unroll
        for (int g = 0; g < 8; ++g) {
            x[2 * g]     = make_float2(pre[g].x, pre[g].y);
            x[2 * g + 1] = make_float2(pre[g].z, pre[g].w);
        }
        if (p < 3) {
            const float2* pn = base + (size_t)(p + 1) * 4096;
#pragma unroll
            for (int g = 0; g < 8; ++g) pre[g] = *(const float4*)(pn + 16 * tid + 2 * g);
        }

        radix16(x, ONE, ONE, ONE, ONE);
        {
            const int i0 = 16 * tid;
#pragma unroll
            for (int s = 0; s < 8; ++s) {
                *(float4*)&z[ZI(i0 + 2 * s)] = make_float4(x[2 * s].x, x[2 * s].y,
                                                           x[2 * s + 1].x, x[2 * s + 1].y);
            }
        }
        lds_barrier();

        // pass 1: st=5, h=16
        {
            const int j = tid & 15;
            const int g = tid >> 4;
            const int i0 = (g << 8) + j;
            int ad[16];
#pragma unroll
            for (int k = 0; k < 16; ++k) ad[k] = ZI(i0 + 16 * k);
#pragma unroll
            for (int k = 0; k < 16; ++k) x[k] = z[ad[k]];
            const float2 tA = ctw4[5 * j + 0];
            const float2 tB = ctw4[5 * j + 1];
            const float2 tC = ctw4[5 * j + 2];
            const float2 tD = ctw4[5 * j + 3];
            radix16(x, tA, tB, tC, tD);
#pragma unroll
            for (int k = 0; k < 16; ++k) z[ad[k]] = x[k];
        }
        lds_barrier();

        // pass 2: st=9, h=256
        {
            const int j = tid;
            int ad[16];
#pragma unroll
            for (int k = 0; k < 16; ++k) ad[k] = ZI(j + 256 * k);
#pragma unroll
            for (int k = 0; k < 16; ++k) x[k] = z[ad[k]];
            float2 a = trig[j << 3], b2 = trig[j << 2], c = trig[j << 1], d = trig[j];
            const float2 tA = make_float2(a.x, -a.y);
            const float2 tB = make_float2(b2.x, -b2.y);
            const float2 tC = make_float2(c.x, -c.y);
            const float2 tD = make_float2(d.x, -d.y);
            radix16(x, tA, tB, tC, tD);
#pragma unroll
            for (int k = 0; k < 16; ++k) z[ad[k]] = x[k];
        }
        lds_barrier();

        // unpack two real spectra; fp16 store (own-region layout); f32 energy accumulation
        {
            const size_t s0 = (size_t)bi * 32768 + (size_t)p * 4096;  // half2 idx, own 128KB region
#pragma unroll
            for (int k = 0; k < 8; ++k) {
                const int t = tid + 256 * k;
                const int m = t + 1;
                float2 Za = z[ZI(m)];
                float2 Zb = z[ZI(4096 - m)];
                float Xr0 = 0.5f * (Za.x + Zb.x);
                float Xi0 = 0.5f * (Za.y - Zb.y);
                float Xr1 = 0.5f * (Za.y + Zb.y);
                float Xi1 = 0.5f * (Zb.x - Za.x);
                Xh[s0 + t]        = __floats2half2_rn(Xr0, Xi0);
                Xh[s0 + 2048 + t] = __floats2half2_rn(Xr1, Xi1);
                eaccr[k] += Xr0 * Xr0 + Xi0 * Xi0 + Xr1 * Xr1 + Xi1 * Xi1;
            }
        }
        lds_barrier();
    }

#pragma unroll
    for (int k = 0; k < 8; ++k) {
        unsigned long long v = (unsigned long long)llrintf(eaccr[k] * 1048576.0f);  // 2^20
        atomicAdd(&score[tid + 256 * k], v);
    }
}

// ---------------- top-64, parallelized: 8 blocks x 256 threads -------------------------------
__global__ __launch_bounds__(256) void k_topk(const unsigned long long* __restrict__ score,
                                              int* __restrict__ idx) {
    __shared__ unsigned long long s[2048];
    const int tid = threadIdx.x;
    for (int t = tid; t < 2048; t += 256) s[t] = score[t];
    __syncthreads();

    const int t = blockIdx.x * 256 + tid;  // 0..2047
    const unsigned long long my = s[t];
    int rank = 0;
#pragma unroll 8
    for (int u = 0; u < 2048; ++u) {
        unsigned long long o = s[u];
        rank += (int)((o > my) || (o == my && u < t));
    }
    if (rank < 64) idx[rank] = t + 1;  // store frequency index m
}

// ---------------- gather + projection -> fp16 Bt for the MFMA synth ---------------------------
// Spectrum layout (per-octet regions): half2 idx of (sig, bin) =
//   (sig>>3)*32768 + ((sig>>1)&3)*4096 + (sig&1)*2048 + bin.
__global__ __launch_bounds__(256) void k_proj(const __half2* __restrict__ Xh,
                                              const float* __restrict__ wr,
                                              const float* __restrict__ wi,
                                              const int* __restrict__ idx,
                                              _Float16* __restrict__ Yt) {
    __shared__ __align__(16) float2 xs[4 * 64];  // [b_loc][e]  2 KB
    __shared__ float  wrs[64 * 64];              // [e][f] 16 KB
    __shared__ float  wis[64 * 64];              // 16 KB

    const int tid = threadIdx.x;
    const int j  = blockIdx.x >> 5;
    const int h  = (blockIdx.x >> 2) & 7;
    const int bq = blockIdx.x & 3;
    const int m = idx[j];

    {
        const int bl = tid >> 6, e = tid & 63;
        const int sig = (((bq * 4 + bl) * 8 + h) * 64 + e);
        const size_t xi = (size_t)(sig >> 3) * 32768 + (size_t)((sig >> 1) & 3) * 4096
                        + (size_t)(sig & 1) * 2048 + (size_t)(m - 1);
        xs[tid] = __half22float2(Xh[xi]);
    }
    const float* wrb = wr + ((size_t)(j * 8 + h)) * 4096;
    const float* wib = wi + ((size_t)(j * 8 + h)) * 4096;
#pragma unroll
    for (int i = 0; i < 16; ++i) {
        const int t = tid + 256 * i;
        wrs[t] = wrb[t];
        wis[t] = wib[t];
    }
    lds_barrier();

    const int bl = tid >> 6;   // 0..3
    const int f  = tid & 63;   // 0..63
    const float2* xrow = &xs[bl * 64];
    float yr = 0.f, yi = 0.f;
#pragma unroll
    for (int e = 0; e < 64; e += 4) {
        const float4 xa = *(const float4*)&xrow[e];
        const float4 xb = *(const float4*)&xrow[e + 2];
        const float2 xv[4] = {make_float2(xa.x, xa.y), make_float2(xa.z, xa.w),
                              make_float2(xb.x, xb.y), make_float2(xb.z, xb.w)};
#pragma unroll
        for (int d = 0; d < 4; ++d) {
            const float a = wrs[(e + d) * 64 + f], cc = wis[(e + d) * 64 + f];
            yr = __builtin_fmaf(xv[d].x, a, yr); yr = __builtin_fmaf(-xv[d].y, cc, yr);
            yi = __builtin_fmaf(xv[d].x, cc, yi); yi = __builtin_fmaf( xv[d].y, a, yi);
        }
    }
    const int b  = bq * 4 + bl;
    const int hf = h * 64 + f;
    _Float16* yt = Yt + ((size_t)b * 512 + (size_t)hf) * 128;
    yt[j]      = (_Float16)(j == 0 ? 0.5f * yr : yr);
    yt[64 + j] = (_Float16)yi;
}

// ---------------- MFMA synthesis: out[b, l, hf] = (2/N) * sum_k Af[l,k] * Yt[b,hf,k] ----------
__global__ __launch_bounds__(256) void k_synth(const _Float16* __restrict__ Af,
                                               const _Float16* __restrict__ Yt,
                                               float* __restrict__ out) {
    const int tid  = threadIdx.x;
    const int wv   = tid >> 6;
    const int lane = tid & 63;
    const int bi   = blockIdx.x;
    const int b    = bi >> 8;         // 16
    const int ng   = (bi >> 6) & 3;   // 4
    const int lt   = bi & 63;         // 64

    const int l0 = lt * 64;
    const int n0 = ng * 128 + wv * 32;

    const int row = lane & 15;        // A-row / B-col / C-col
    const int kb  = lane >> 4;        // k-block 0..3

    f32x4 acc[4][2] = {};

    const _Float16* Ab = Af + (size_t)l0 * 128;
    const _Float16* Bb = Yt + (size_t)b * 512 * 128 + (size_t)n0 * 128;

#pragma unroll
    for (int k0 = 0; k0 < 128; k0 += 32) {
        f16x8 a[4], bf[2];
#pragma unroll
        for (int mt = 0; mt < 4; ++mt)
            a[mt] = *(const f16x8*)(Ab + (size_t)(mt * 16 + row) * 128 + k0 + kb * 8);
#pragma unroll
        for (int nt = 0; nt < 2; ++nt)
            bf[nt] = *(const f16x8*)(Bb + (size_t)(nt * 16 + row) * 128 + k0 + kb * 8);
#pragma unroll
        for (int mt = 0; mt < 4; ++mt)
#pragma unroll
            for (int nt = 0; nt < 2; ++nt)
                acc[mt][nt] = __builtin_amdgcn_mfma_f32_16x16x32_f16(a[mt], bf[nt],
                                                                     acc[mt][nt], 0, 0, 0);
    }

    const float s = 2.0f / 4096.0f;
#pragma unroll
    for (int mt = 0; mt < 4; ++mt) {
#pragma unroll
        for (int nt = 0; nt < 2; ++nt) {
            const int col = n0 + nt * 16 + row;  // hf
#pragma unroll
            for (int r = 0; r < 4; ++r) {
                const int mrow = mt * 16 + kb * 4 + r;
                out[((size_t)(b * 4096 + l0 + mrow)) * 512 + col] = acc[mt][nt][r] * s;
            }
        }
    }
}

// ---------------- launch ----------------
extern "C" void kernel_launch(void* const* d_in, const int* in_sizes, int n_in,
                              void* d_out, int out_size, void* d_ws, size_t ws_size,
                              hipStream_t stream) {
    const float* q  = (const float*)d_in[0];
    const float* wr = (const float*)d_in[3];
    const float* wi = (const float*)d_in[4];

    char* ws = (char*)d_ws;
    float2*             trig  = (float2*)(ws + 0);                  // 32 KB
    unsigned long long* score = (unsigned long long*)(ws + 32768);  // 16 KB
    int*                idx   = (int*)(ws + 49152);                 // 256 B
    _Float16*           Af    = (_Float16*)(ws + 65536);            // 1 MB
    _Float16*           Yt    = (_Float16*)(ws + 65536 + 1048576);  // 2 MB

    // d_out triples as: transposed-q scratch T -> fp16 spectrum (in-place, per-octet regions)
    // -> final output.
    float2* Xs = (float2*)d_out;

    k_init<<<2064, 256, 0, stream>>>(trig, score, Af);   // trig + score + Af in one dispatch
    k_xpose<<<8192, 256, 0, stream>>>(q, Xs);            // (b:16, h:8, c6:64), 64-row tiles
    k_fft<<<1024, 256, 0, stream>>>(trig, Xs, score);    // R20: 4 planes/block, prefetch
    k_topk<<<8, 256, 0, stream>>>(score, idx);           // 2048 candidates, 1/thread
    k_proj<<<2048, 256, 0, stream>>>((const __half2*)Xs, wr, wi, idx, Yt);  // -> fp16 Bt
    k_synth<<<4096, 256, 0, stream>>>(Af, Yt, (float*)d_out);               // MFMA GEMM
}